// Round 3
// baseline (190.204 us; speedup 1.0000x reference)
//
#include <hip/hip_runtime.h>

#define NPTS 65536
#define CCH  32
#define DDIM 64
#define GVOX (DDIM*DDIM*DDIM)   // B=1 -> 262144 voxels
#define MAXTILES 4128           // >= 65536/16 + 27 (per-class padding)
#define NSLOTCAP (MAXTILES*16)  // zero-row sentinel index
#define NCELL 512               // 8x8x8 coarse cells
#define KEYS (27*NCELL)         // 13824 (class, cell) keys
#define KEYSP 14336             // padded to 256*56 for aligned per-thread chunks
#define CHUNKP 56

typedef _Float16 half8  __attribute__((ext_vector_type(8)));
typedef _Float16 half4v __attribute__((ext_vector_type(4)));
typedef float    floatx4 __attribute__((ext_vector_type(4)));

// ---------------- prep0: init (one launch) ----------------
__global__ __launch_bounds__(256) void k_prep0(
    int* __restrict__ map, int* __restrict__ sorted, int* __restrict__ pcoords,
    const float* __restrict__ k1, const float* __restrict__ k2,
    _Float16* __restrict__ w1, _Float16* __restrict__ w2,
    _Float16* __restrict__ valsh, _Float16* __restrict__ hh,
    int* __restrict__ cntslot)             // [cnt | slot], 2*KEYSP ints
{
  int tid = blockIdx.x * 256 + threadIdx.x;
  if (tid < GVOX/4) { ((int4*)map)[tid] = make_int4(-1,-1,-1,-1); return; }
  tid -= GVOX/4;
  if (tid < NSLOTCAP/4) { ((int4*)sorted)[tid] = make_int4(NPTS,NPTS,NPTS,NPTS); return; }
  tid -= NSLOTCAP/4;
  if (tid < NSLOTCAP/4) { ((int4*)pcoords)[tid] = make_int4(0,0,0,0); return; }
  tid -= NSLOTCAP/4;
  if (tid < 27*CCH*CCH) {                  // (t,cin,cout) f32 -> (t,cout,cin) f16
    int t = tid/(CCH*CCH), r = tid%(CCH*CCH);
    int cin = r/CCH, cout = r%CCH;
    int o = (t*CCH + cout)*CCH + cin;
    w1[o] = (_Float16)k1[tid]; w2[o] = (_Float16)k2[tid]; return;
  }
  tid -= 27*CCH*CCH;
  if (tid < CCH) {                         // zero sentinel rows (empty-voxel gather)
    valsh[NSLOTCAP*CCH + tid] = (_Float16)0.f;
    hh[NSLOTCAP*CCH + tid]    = (_Float16)0.f; return;
  }
  tid -= CCH;
  if (tid < (2*KEYSP)/4) { ((int4*)cntslot)[tid] = make_int4(0,0,0,0); return; }
}
#define PREP0_THREADS (GVOX/4 + NSLOTCAP/4 + NSLOTCAP/4 + 27*CCH*CCH + CCH + (2*KEYSP)/4)

// ---------------- prep1: (class, cell) key + packed coords + histogram -------
__global__ __launch_bounds__(256) void k_prep1(const int* __restrict__ idx,
                                               int* __restrict__ key,
                                               int* __restrict__ pk,
                                               int* __restrict__ cnt)
{
  const int n = blockIdx.x*256 + threadIdx.x;
  const int4 v = ((const int4*)idx)[n];
  const int b = v.x, z = v.y, y = v.z, x = v.w;
  pk[n] = (b<<18) | (z<<12) | (y<<6) | x;
  const int cz = (z==0)?0:((z==DDIM-1)?2:1);
  const int cy = (y==0)?0:((y==DDIM-1)?2:1);
  const int cx = (x==0)?0:((x==DDIM-1)?2:1);
  const int c = cz*9 + cy*3 + cx;
  const int cell = ((z>>3)<<6) | ((y>>3)<<3) | (x>>3);
  const int k = (c<<9) | cell;
  key[n] = k;
  atomicAdd(&cnt[k], 1);
}

// ---------------- k_scan: parallel exclusive scan over padded keys -----------
// Independent int4 loads -> register scan -> Hillis-Steele across threads.
__global__ __launch_bounds__(256) void k_scan(const int* __restrict__ cnt,
                                              int* __restrict__ keybase,
                                              int* __restrict__ tstart,
                                              int* __restrict__ ntiles)
{
  __shared__ int E[KEYSP];                 // 56 KB
  __shared__ int ts[256];
  __shared__ int clsb[27], clsu[27];
  const int t = threadIdx.x;
  int4 vv[CHUNKP/4];
#pragma unroll
  for (int i = 0; i < CHUNKP/4; ++i) vv[i] = ((const int4*)cnt)[t*(CHUNKP/4) + i];
  int e[CHUNKP];
  int run = 0;
#pragma unroll
  for (int i = 0; i < CHUNKP/4; ++i) {
    e[4*i+0] = run; run += vv[i].x;
    e[4*i+1] = run; run += vv[i].y;
    e[4*i+2] = run; run += vv[i].z;
    e[4*i+3] = run; run += vv[i].w;
  }
  ts[t] = run;
  __syncthreads();
  for (int d = 1; d < 256; d <<= 1) {      // inclusive scan, 8 steps
    const int val = (t >= d) ? ts[t-d] : 0;
    __syncthreads();
    ts[t] += val;
    __syncthreads();
  }
  const int off = ts[t] - run;             // exclusive prefix for this thread
#pragma unroll
  for (int i = 0; i < CHUNKP; ++i) E[t*CHUNKP + i] = e[i] + off;
  __syncthreads();
  if (t == 0) {
    int b = 0, tb = 0;
    for (int c = 0; c < 27; ++c) {
      const int start = E[c*NCELL];
      const int end   = E[(c+1)*NCELL];    // E[13824] = total = NPTS
      clsu[c] = start; clsb[c] = b; tstart[c] = tb;
      const int ntc = (end - start + 15) >> 4;
      b += ntc << 4; tb += ntc;
    }
    tstart[27] = tb; *ntiles = tb;
  }
  __syncthreads();
#pragma unroll
  for (int i = 0; i < CHUNKP; ++i) {
    const int k = t*CHUNKP + i;
    if (k < KEYS) {
      const int c = k >> 9;
      keybase[k] = clsb[c] + (E[k] - clsu[c]);
    }
  }
}

// ---------------- prep3: scatter 4B ranks only + tile class table -----------
__global__ __launch_bounds__(256) void k_prep3(const int* __restrict__ key,
                                               const int* __restrict__ pk,
                                               const int* __restrict__ keybase,
                                               int* __restrict__ slot,
                                               int* __restrict__ sorted,
                                               int* __restrict__ map,
                                               int* __restrict__ pcoords,
                                               const int* __restrict__ tstart,
                                               int* __restrict__ tileclass,
                                               const int* __restrict__ ntp)
{
  if (blockIdx.x < NPTS/256) {
    const int n = blockIdx.x*256 + threadIdx.x;
    const int k = key[n], p = pk[n];
    const int s = keybase[k] + atomicAdd(&slot[k], 1);
    sorted[s] = n;
    pcoords[s] = p;
    map[p] = s;
  } else {
    const int i = (blockIdx.x - NPTS/256)*256 + threadIdx.x;
    if (i >= MAXTILES) return;
    const int nt = *ntp;
    int c = 13;
    if (i < nt) {
      for (int cc = 0; cc < 27; ++cc)
        if (i >= tstart[cc] && i < tstart[cc+1]) { c = cc; break; }
    }
    tileclass[i] = c;
  }
}

// ---------------- prep4: gather-convert values -> slot-ordered f16 ----------
// Random coalesced reads (permutation, each line once) + sequential writes.
__global__ __launch_bounds__(256) void k_prep4(const int* __restrict__ sorted,
                                               const float* __restrict__ values,
                                               _Float16* __restrict__ valsh)
{
  const int tid = blockIdx.x*256 + threadIdx.x;
  const int s = tid >> 3, part = tid & 7;
  const int n = sorted[s];
  if (n >= NPTS) return;
  const float4 v = *(const float4*)(values + n*CCH + part*4);
  const half4v h = {(_Float16)v.x, (_Float16)v.y, (_Float16)v.z, (_Float16)v.w};
  *(half4v*)(valsh + s*CCH + part*4) = h;
}

// ---------------- unified gather-MFMA conv, tap-split across 2 waves ---------
// A table is SLOT-indexed (sorted rank): map[voxel] = slot, empty = -1 -> zero
// row NSLOTCAP. Points in a tile share one 8^3 cell, so map/A gathers stay in
// a small L1-resident window across all 27 taps.
template<int J0, int J1>
__device__ __forceinline__ void accum_taps(
    const _Float16* __restrict__ A, const int* __restrict__ map,
    const _Float16* __restrict__ WT,
    int cz, int cy, int cx, int linb,
    const int* az, const int* ay, const int* ax,
    int m, int quad, floatx4& acc0, floatx4& acc1)
{
  int srcs[J1 - J0];
#pragma unroll
  for (int j = J0; j < J1; ++j) {
    const int jz = j/9, jy = (j/3)%3, jx = j%3;
    const int s = map[linb | az[jz] | ay[jy] | ax[jx]];
    srcs[j - J0] = (s < 0) ? (NSLOTCAP*CCH) : (s*CCH);
  }
#pragma unroll
  for (int j = J0; j < J1; ++j) {
    const int jz = j/9, jy = (j/3)%3, jx = j%3;
    const int tz = (cz==1) ? (2-jz) : ((jz==1) ? 1 : ((cz==0) ? 0 : 2));
    const int ty = (cy==1) ? (2-jy) : ((jy==1) ? 1 : ((cy==0) ? 0 : 2));
    const int tx = (cx==1) ? (2-jx) : ((jx==1) ? 1 : ((cx==0) ? 0 : 2));
    const int t  = tz*9 + ty*3 + tx;
    half8 a  = *(const half8*)(A + srcs[j - J0] + quad*8);
    const _Float16* wr = WT + t*(CCH*CCH);
    half8 b0 = *(const half8*)(wr + m*CCH + quad*8);
    half8 b1 = *(const half8*)(wr + (16+m)*CCH + quad*8);
    acc0 = __builtin_amdgcn_mfma_f32_16x16x32_f16(a, b0, acc0, 0, 0, 0);
    acc1 = __builtin_amdgcn_mfma_f32_16x16x32_f16(a, b1, acc1, 0, 0, 0);
  }
}

template<int MODE>
__global__ __launch_bounds__(256) void conv_mfma(
    const _Float16* __restrict__ A,        // (NSLOTCAP+1) x 32 f16, row NSLOTCAP = zeros
    const int* __restrict__ map,
    const int* __restrict__ pcoords,       // slot-indexed packed coords
    const int* __restrict__ sorted,        // slot -> original pid
    const int* __restrict__ tileclass,
    const int* __restrict__ ntp,
    const _Float16* __restrict__ WT,       // 27 x cout x cin f16
    const float* __restrict__ bias,
    const float* __restrict__ mask,
    const float* __restrict__ resid,
    _Float16* __restrict__ hout,           // slot-indexed
    float* __restrict__ fout)              // pid-indexed
{
  __shared__ float red[2][16][33];
  const int wv   = threadIdx.x >> 6;
  const int tl   = wv >> 1;
  const int half = wv & 1;
  const int tile = blockIdx.x*2 + tl;
  const int nt   = *ntp;
  const bool active = tile < nt;
  const int lane = threadIdx.x & 63;
  const int m = lane & 15, quad = lane >> 4;

  floatx4 acc0 = {0.f,0.f,0.f,0.f};
  floatx4 acc1 = {0.f,0.f,0.f,0.f};

  if (active) {
    const int scls = __builtin_amdgcn_readfirstlane(tileclass[tile]);
    const int cz = scls/9, cy = (scls/3)%3, cx = scls%3;
    const int pc = pcoords[tile*16 + m];
    const int bb = pc>>18, z = (pc>>12)&63, y = (pc>>6)&63, x = pc&63;
    const int linb = bb << 18;
    const int az[3] = { max(z-1,0)<<12, z<<12, min(z+1,DDIM-1)<<12 };
    const int ay[3] = { max(y-1,0)<<6,  y<<6,  min(y+1,DDIM-1)<<6 };
    const int ax[3] = { max(x-1,0),     x,     min(x+1,DDIM-1) };
    if (half == 0)
      accum_taps<0,14>(A, map, WT, cz,cy,cx, linb, az,ay,ax, m,quad, acc0,acc1);
    else
      accum_taps<14,27>(A, map, WT, cz,cy,cx, linb, az,ay,ax, m,quad, acc0,acc1);
  }

  if (active && half == 0) {
#pragma unroll
    for (int r = 0; r < 4; ++r) {
      red[tl][quad*4+r][m]    = acc0[r];
      red[tl][quad*4+r][m+16] = acc1[r];
    }
  }
  __syncthreads();
  if (active && half == 1) {
#pragma unroll
    for (int r = 0; r < 4; ++r) {
      acc0[r] += red[tl][quad*4+r][m];
      acc1[r] += red[tl][quad*4+r][m+16];
    }
    const float bi0 = bias[m], bi1 = bias[m+16];
#pragma unroll
    for (int reg = 0; reg < 4; ++reg) {
      const int r    = quad*4 + reg;
      const int srow = tile*16 + r;
      const int pr   = sorted[srow];
      if (pr >= NPTS) continue;            // padded slot
      const float mk = mask[pr];
      float v0 = (acc0[reg] + mk*bi0) * mk;
      float v1 = (acc1[reg] + mk*bi1) * mk;
      if (MODE == 0) {
        v0 = fmaxf(v0, 0.f); v1 = fmaxf(v1, 0.f);
        hout[srow*CCH + m]      = (_Float16)v0;   // contiguous per tile
        hout[srow*CCH + m + 16] = (_Float16)v1;
      } else {
        fout[pr*CCH + m]      = resid[pr*CCH + m]      + v0;
        fout[pr*CCH + m + 16] = resid[pr*CCH + m + 16] + v1;
      }
    }
  }
}

// ---------------- launch ----------------

extern "C" void kernel_launch(void* const* d_in, const int* in_sizes, int n_in,
                              void* d_out, int out_size, void* d_ws, size_t ws_size,
                              hipStream_t stream) {
  const float* values = (const float*)d_in[0];
  const int*   indices= (const int*)  d_in[1];
  const float* maskv  = (const float*)d_in[2];
  const float* kern1  = (const float*)d_in[3];
  const float* bias1  = (const float*)d_in[4];
  const float* kern2  = (const float*)d_in[5];
  const float* bias2  = (const float*)d_in[6];
  float* out = (float*)d_out;

  char* ws = (char*)d_ws;
  size_t off = 0;
  auto alloc = [&](size_t bytes) { void* p = ws + off; off = (off + bytes + 255) & ~(size_t)255; return p; };
  int*      map      = (int*)     alloc(GVOX*4);                   // 1 MB
  int*      key      = (int*)     alloc(NPTS*4);
  int*      pk       = (int*)     alloc(NPTS*4);
  int*      sorted   = (int*)     alloc(NSLOTCAP*4);
  int*      pcoords  = (int*)     alloc(NSLOTCAP*4);
  int*      tileclass= (int*)     alloc(MAXTILES*4);
  int*      cntslot  = (int*)     alloc(2*KEYSP*4);                // cnt | slot
  int*      keybase  = (int*)     alloc(KEYS*4);
  int*      tstart   = (int*)     alloc(28*4);
  int*      ntiles   = (int*)     alloc(4);
  _Float16* valsh    = (_Float16*)alloc((size_t)(NSLOTCAP+1)*CCH*2);  // ~4.2 MB
  _Float16* hh       = (_Float16*)alloc((size_t)(NSLOTCAP+1)*CCH*2);  // ~4.2 MB
  _Float16* wt1      = (_Float16*)alloc(27*CCH*CCH*2);
  _Float16* wt2      = (_Float16*)alloc(27*CCH*CCH*2);
  int* cnt  = cntslot;
  int* slot = cntslot + KEYSP;

  k_prep0<<<(PREP0_THREADS + 255)/256, 256, 0, stream>>>(
      map, sorted, pcoords, kern1, kern2, wt1, wt2, valsh, hh, cntslot);
  k_prep1<<<NPTS/256, 256, 0, stream>>>(indices, key, pk, cnt);
  k_scan<<<1, 256, 0, stream>>>(cnt, keybase, tstart, ntiles);
  k_prep3<<<NPTS/256 + (MAXTILES+255)/256, 256, 0, stream>>>(
      key, pk, keybase, slot, sorted, map, pcoords, tstart, tileclass, ntiles);
  k_prep4<<<(NSLOTCAP*8)/256, 256, 0, stream>>>(sorted, values, valsh);

  conv_mfma<0><<<MAXTILES/2, 256, 0, stream>>>(valsh, map, pcoords, sorted, tileclass,
                                               ntiles, wt1, bias1, maskv, nullptr, hh, nullptr);
  conv_mfma<1><<<MAXTILES/2, 256, 0, stream>>>(hh, map, pcoords, sorted, tileclass,
                                               ntiles, wt2, bias2, maskv, values, nullptr, out);
}

// Round 4
// 141.124 us; speedup vs baseline: 1.3478x; 1.3478x over previous
//
#include <hip/hip_runtime.h>

#define NPTS 65536
#define CCH  32
#define DDIM 64
#define GVOX (DDIM*DDIM*DDIM)   // B=1 -> 262144 voxels
#define MAXTILES 4128           // >= 65536/16 + 27 (per-class padding)

typedef _Float16 half8  __attribute__((ext_vector_type(8)));
typedef _Float16 half4v __attribute__((ext_vector_type(4)));
typedef float    floatx4 __attribute__((ext_vector_type(4)));

// ---------------- prep0: init + dtype conversion (one launch) ----------------
// ranges: map init | sorted init | values->f16 | weight transpose | zero rows | counters
__global__ __launch_bounds__(256) void k_prep0(
    int* __restrict__ map, int* __restrict__ sorted,
    const float* __restrict__ values, _Float16* __restrict__ valsh,
    const float* __restrict__ k1, const float* __restrict__ k2,
    _Float16* __restrict__ w1, _Float16* __restrict__ w2,
    _Float16* __restrict__ hh, int* __restrict__ pcoord,
    int* __restrict__ cnt, int* __restrict__ slot)
{
  int tid = blockIdx.x * 256 + threadIdx.x;
  if (tid < GVOX/4) { ((int4*)map)[tid] = make_int4(-1,-1,-1,-1); return; }
  tid -= GVOX/4;
  if (tid < MAXTILES*16) { sorted[tid] = NPTS; return; }
  tid -= MAXTILES*16;
  if (tid < (NPTS*CCH)/4) {
    float4 v = ((const float4*)values)[tid];
    half4v h = { (_Float16)v.x, (_Float16)v.y, (_Float16)v.z, (_Float16)v.w };
    ((half4v*)valsh)[tid] = h; return;
  }
  tid -= (NPTS*CCH)/4;
  if (tid < 27*CCH*CCH) {                       // (t,cin,cout) f32 -> (t,cout,cin) f16
    int t = tid/(CCH*CCH), r = tid%(CCH*CCH);
    int cin = r/CCH, cout = r%CCH;
    int o = (t*CCH + cout)*CCH + cin;
    w1[o] = (_Float16)k1[tid]; w2[o] = (_Float16)k2[tid]; return;
  }
  tid -= 27*CCH*CCH;
  if (tid < CCH) { valsh[NPTS*CCH+tid] = (_Float16)0.f; hh[NPTS*CCH+tid] = (_Float16)0.f; return; }
  tid -= CCH;
  if (tid < 27) { cnt[tid] = 0; slot[tid] = 0; return; }
  tid -= 27;
  if (tid == 0) pcoord[NPTS] = 0;               // sentinel point coords
}
#define PREP0_THREADS (GVOX/4 + MAXTILES*16 + (NPTS*CCH)/4 + 27*CCH*CCH + CCH + 27 + 1)

// ---------------- prep1: map + pcoord + class histogram ----------------
__global__ __launch_bounds__(256) void k_prep1(const int* __restrict__ idx,
                                               int* __restrict__ map,
                                               int* __restrict__ pcoord,
                                               int* __restrict__ cls,
                                               int* __restrict__ cnt)
{
  __shared__ int lcnt[27];
  if (threadIdx.x < 27) lcnt[threadIdx.x] = 0;
  __syncthreads();
  const int n = blockIdx.x*256 + threadIdx.x;
  const int4 v = ((const int4*)idx)[n];
  const int b = v.x, z = v.y, y = v.z, x = v.w;
  map[((b*DDIM + z)*DDIM + y)*DDIM + x] = n;
  pcoord[n] = (b<<18) | (z<<12) | (y<<6) | x;
  const int cz = (z==0)?0:((z==DDIM-1)?2:1);
  const int cy = (y==0)?0:((y==DDIM-1)?2:1);
  const int cx = (x==0)?0:((x==DDIM-1)?2:1);
  const int c = cz*9 + cy*3 + cx;
  cls[n] = c;
  atomicAdd(&lcnt[c], 1);
  __syncthreads();
  if (threadIdx.x < 27 && lcnt[threadIdx.x]) atomicAdd(&cnt[threadIdx.x], lcnt[threadIdx.x]);
}

// ---------------- prep3: per-block 27-class scan + scatter + tile class ------
__global__ __launch_bounds__(256) void k_prep3(const int* __restrict__ cls,
                                               const int* __restrict__ cnt,
                                               int* __restrict__ slot,
                                               int* __restrict__ sorted,
                                               int* __restrict__ tileclass,
                                               int* __restrict__ ntiles)
{
  __shared__ int s_clsbase[27];
  __shared__ int s_tstart[28];
  if (threadIdx.x == 0) {
    int b = 0, tb = 0;
#pragma unroll
    for (int c = 0; c < 27; ++c) {
      s_clsbase[c] = b; s_tstart[c] = tb;
      const int ntc = (cnt[c] + 15) >> 4;
      b += ntc << 4; tb += ntc;
    }
    s_tstart[27] = tb;
    if (blockIdx.x == 0) *ntiles = tb;
  }
  __syncthreads();

  if (blockIdx.x < NPTS/256) {
    __shared__ int lcnt[27], lbase[27];
    if (threadIdx.x < 27) lcnt[threadIdx.x] = 0;
    __syncthreads();
    const int n = blockIdx.x*256 + threadIdx.x;
    const int c = cls[n];
    const int lrank = atomicAdd(&lcnt[c], 1);
    __syncthreads();
    if (threadIdx.x < 27)
      lbase[threadIdx.x] = lcnt[threadIdx.x] ? atomicAdd(&slot[threadIdx.x], lcnt[threadIdx.x]) : 0;
    __syncthreads();
    sorted[s_clsbase[c] + lbase[c] + lrank] = n;
  } else {
    const int i = (blockIdx.x - NPTS/256)*256 + threadIdx.x;
    if (i >= MAXTILES) return;
    const int nt = s_tstart[27];
    int c = 13;
    if (i < nt) {
      for (int cc = 0; cc < 27; ++cc)
        if (i >= s_tstart[cc] && i < s_tstart[cc+1]) { c = cc; break; }
    }
    tileclass[i] = c;
  }
}

// ---------------- unified gather-MFMA conv, LDS weights + 2-wave tap split ---
// 512 threads = 8 waves = 4 tiles x 2 tap-halves. All 27 taps' weights
// (55.3 KB) staged in LDS once per block; B-reads are conflict-free linear
// ds_read_b128 sweeps (lane (m,quad) -> distinct 16B chunk of a 1KB region).
// This halves L1 line-touches per tap and frees L1 for the map/A gathers.
template<int J0, int J1>
__device__ __forceinline__ void accum_taps(
    const _Float16* __restrict__ A, const int* __restrict__ map,
    const _Float16* lw,                    // LDS weights: 27 x cout x cin
    int cz, int cy, int cx, int linb,
    const int* az, const int* ay, const int* ax,
    int m, int quad, floatx4& acc0, floatx4& acc1)
{
  int srcs[J1 - J0];
#pragma unroll
  for (int j = J0; j < J1; ++j) {
    const int jz = j/9, jy = (j/3)%3, jx = j%3;
    const int s = map[linb | az[jz] | ay[jy] | ax[jx]];
    srcs[j - J0] = (s < 0) ? (NPTS*CCH) : (s*CCH);   // empty voxel -> zero row
  }
#pragma unroll
  for (int j = J0; j < J1; ++j) {
    const int jz = j/9, jy = (j/3)%3, jx = j%3;
    // per-dim tap index given class (jz/jy/jx compile-time, class wave-uniform)
    const int tz = (cz==1) ? (2-jz) : ((jz==1) ? 1 : ((cz==0) ? 0 : 2));
    const int ty = (cy==1) ? (2-jy) : ((jy==1) ? 1 : ((cy==0) ? 0 : 2));
    const int tx = (cx==1) ? (2-jx) : ((jx==1) ? 1 : ((cx==0) ? 0 : 2));
    const int t  = tz*9 + ty*3 + tx;
    half8 a  = *(const half8*)(A + srcs[j - J0] + quad*8);
    const _Float16* wr = lw + t*(CCH*CCH);
    half8 b0 = *(const half8*)(wr + m*CCH + quad*8);
    half8 b1 = *(const half8*)(wr + (16+m)*CCH + quad*8);
    acc0 = __builtin_amdgcn_mfma_f32_16x16x32_f16(a, b0, acc0, 0, 0, 0);
    acc1 = __builtin_amdgcn_mfma_f32_16x16x32_f16(a, b1, acc1, 0, 0, 0);
  }
}

template<int MODE>
__global__ __launch_bounds__(512) void conv_mfma(
    const _Float16* __restrict__ A,        // (NPTS+1) x 32 f16, row NPTS = zeros
    const int* __restrict__ map,
    const int* __restrict__ pcoord,
    const int* __restrict__ sorted,
    const int* __restrict__ tileclass,
    const int* __restrict__ ntp,
    const _Float16* __restrict__ WT,       // 27 x cout x cin f16
    const float* __restrict__ bias,
    const float* __restrict__ mask,
    const float* __restrict__ resid,
    _Float16* __restrict__ hout,
    float* __restrict__ fout)
{
  __shared__ _Float16 lw[27*CCH*CCH];      // 55296 B
  __shared__ float red[4][16][33];         // 8448 B (stride 33 breaks aliasing)

  // stage weights: 27648 halfs = 3456 x 16B, 512 threads
  for (int i = threadIdx.x; i < 3456; i += 512)
    ((half8*)lw)[i] = ((const half8*)WT)[i];

  const int wv   = threadIdx.x >> 6;       // 0..7
  const int tl   = wv >> 1;                // tile slot within block (0..3)
  const int half = wv & 1;                 // tap-half
  const int tile = blockIdx.x*4 + tl;
  const int nt   = *ntp;
  const bool active = tile < nt;
  const int lane = threadIdx.x & 63;
  const int m = lane & 15, quad = lane >> 4;

  floatx4 acc0 = {0.f,0.f,0.f,0.f};
  floatx4 acc1 = {0.f,0.f,0.f,0.f};

  int scls = 13, pc = 0;
  if (active) {
    scls = __builtin_amdgcn_readfirstlane(tileclass[tile]);
    const int pid = sorted[tile*16 + m];
    pc = pcoord[pid];
  }
  __syncthreads();                          // weights staged

  if (active) {
    const int cz = scls/9, cy = (scls/3)%3, cx = scls%3;
    const int bb = pc>>18, z = (pc>>12)&63, y = (pc>>6)&63, x = pc&63;
    const int linb = bb << 18;
    const int az[3] = { max(z-1,0)<<12, z<<12, min(z+1,DDIM-1)<<12 };
    const int ay[3] = { max(y-1,0)<<6,  y<<6,  min(y+1,DDIM-1)<<6 };
    const int ax[3] = { max(x-1,0),     x,     min(x+1,DDIM-1) };
    if (half == 0)
      accum_taps<0,14>(A, map, lw, cz,cy,cx, linb, az,ay,ax, m,quad, acc0,acc1);
    else
      accum_taps<14,27>(A, map, lw, cz,cy,cx, linb, az,ay,ax, m,quad, acc0,acc1);
  }

  if (active && half == 0) {
#pragma unroll
    for (int r = 0; r < 4; ++r) {
      red[tl][quad*4+r][m]    = acc0[r];
      red[tl][quad*4+r][m+16] = acc1[r];
    }
  }
  __syncthreads();
  if (active && half == 1) {
#pragma unroll
    for (int r = 0; r < 4; ++r) {
      acc0[r] += red[tl][quad*4+r][m];
      acc1[r] += red[tl][quad*4+r][m+16];
    }
    // D layout: col(N=cout) = lane&15, row(M=point) = quad*4 + reg
    const float bi0 = bias[m], bi1 = bias[m+16];
#pragma unroll
    for (int reg = 0; reg < 4; ++reg) {
      const int r  = quad*4 + reg;
      const int pr = sorted[tile*16 + r];
      if (pr >= NPTS) continue;            // padded lane
      const float mk = mask[pr];
      float v0 = (acc0[reg] + mk*bi0) * mk;
      float v1 = (acc1[reg] + mk*bi1) * mk;
      if (MODE == 0) {
        v0 = fmaxf(v0, 0.f); v1 = fmaxf(v1, 0.f);
        hout[pr*CCH + m]      = (_Float16)v0;
        hout[pr*CCH + m + 16] = (_Float16)v1;
      } else {
        fout[pr*CCH + m]      = resid[pr*CCH + m]      + v0;
        fout[pr*CCH + m + 16] = resid[pr*CCH + m + 16] + v1;
      }
    }
  }
}

// ---------------- launch ----------------

extern "C" void kernel_launch(void* const* d_in, const int* in_sizes, int n_in,
                              void* d_out, int out_size, void* d_ws, size_t ws_size,
                              hipStream_t stream) {
  const float* values = (const float*)d_in[0];
  const int*   indices= (const int*)  d_in[1];
  const float* maskv  = (const float*)d_in[2];
  const float* kern1  = (const float*)d_in[3];
  const float* bias1  = (const float*)d_in[4];
  const float* kern2  = (const float*)d_in[5];
  const float* bias2  = (const float*)d_in[6];
  float* out = (float*)d_out;

  char* ws = (char*)d_ws;
  size_t off = 0;
  auto alloc = [&](size_t bytes) { void* p = ws + off; off = (off + bytes + 255) & ~(size_t)255; return p; };
  int*      map      = (int*)     alloc(GVOX*4);            // 1 MB
  int*      pcoord   = (int*)     alloc((NPTS+1)*4);
  int*      cls      = (int*)     alloc(NPTS*4);
  int*      sorted   = (int*)     alloc(MAXTILES*16*4);
  int*      tileclass= (int*)     alloc(MAXTILES*4);
  int*      cnt      = (int*)     alloc(27*4);
  int*      slot     = (int*)     alloc(27*4);
  int*      ntiles   = (int*)     alloc(4);
  _Float16* valsh    = (_Float16*)alloc((NPTS+1)*CCH*2);    // 4 MB
  _Float16* hh       = (_Float16*)alloc((NPTS+1)*CCH*2);    // 4 MB
  _Float16* wt1      = (_Float16*)alloc(27*CCH*CCH*2);
  _Float16* wt2      = (_Float16*)alloc(27*CCH*CCH*2);

  k_prep0<<<(PREP0_THREADS + 255)/256, 256, 0, stream>>>(
      map, sorted, values, valsh, kern1, kern2, wt1, wt2, hh, pcoord, cnt, slot);
  k_prep1<<<NPTS/256, 256, 0, stream>>>(indices, map, pcoord, cls, cnt);
  k_prep3<<<NPTS/256 + (MAXTILES+255)/256, 256, 0, stream>>>(
      cls, cnt, slot, sorted, tileclass, ntiles);

  conv_mfma<0><<<MAXTILES/4, 512, 0, stream>>>(valsh, map, pcoord, sorted, tileclass,
                                               ntiles, wt1, bias1, maskv, nullptr, hh, nullptr);
  conv_mfma<1><<<MAXTILES/4, 512, 0, stream>>>(hh, map, pcoord, sorted, tileclass,
                                               ntiles, wt2, bias2, maskv, values, nullptr, out);
}

// Round 7
// 140.372 us; speedup vs baseline: 1.3550x; 1.0054x over previous
//
#include <hip/hip_runtime.h>
#include <hip/hip_cooperative_groups.h>

namespace cg = cooperative_groups;

#define NPTS 65536
#define CCH  32
#define DDIM 64
#define GVOX (DDIM*DDIM*DDIM)   // B=1 -> 262144 voxels
#define MAXTILES 4128           // >= 65536/16 + 27 (per-class padding)
#define NTHREADS 1024
#define NBLOCKS  256            // 1 block/CU guaranteed (55.7 KB LDS <= 64 KB)
#define TTOT (NTHREADS*NBLOCKS)

typedef _Float16 half8  __attribute__((ext_vector_type(8)));
typedef _Float16 half4v __attribute__((ext_vector_type(4)));
typedef float    floatx4 __attribute__((ext_vector_type(4)));

// P0 work items: map | sorted | values->f16 | weights | zero rows | cnt+slot | sentinel
#define P0N (GVOX/4 + MAXTILES*16 + (NPTS*CCH)/4 + 27*CCH*CCH + CCH + 27 + 1)

// ============================================================================
// Fused cooperative kernel
// ============================================================================
struct SharedC {
  _Float16 lw[27*CCH*CCH];   // 55296 B: all 27 taps' weights (cout x cin)
  int tstart[28];
  int clsbase[27];
  int lcnt[27];
  int lbase[27];
};

template<int MODE>
__device__ void conv_phase_c(SharedC& sh,
    const _Float16* __restrict__ A, const int* __restrict__ map,
    const int* __restrict__ pcoord, const int* __restrict__ sorted,
    const _Float16* __restrict__ WT, const float* __restrict__ bias,
    const float* __restrict__ mask, const float* __restrict__ resid,
    _Float16* __restrict__ hout, float* __restrict__ fout)
{
  for (int i = threadIdx.x; i < (27*CCH*CCH)/8; i += NTHREADS)
    ((half8*)sh.lw)[i] = ((const half8*)WT)[i];
  __syncthreads();

  const int wv   = threadIdx.x >> 6;       // 0..15 (wave = 1 tile, 27 taps)
  const int lane = threadIdx.x & 63;
  const int m = lane & 15, quad = lane >> 4;
  const int nt = sh.tstart[27];
  const float bi0 = bias[m], bi1 = bias[m+16];

  for (int tile = blockIdx.x*(NTHREADS/64) + wv; tile < nt;
       tile += NBLOCKS*(NTHREADS/64)) {
    int scls = 0;
    for (int cc = 1; cc < 27; ++cc) if (tile >= sh.tstart[cc]) scls = cc;
    scls = __builtin_amdgcn_readfirstlane(scls);
    const int cz = scls/9, cy = (scls/3)%3, cx = scls%3;

    const int pid = sorted[tile*16 + m];
    const int pc  = pcoord[pid];
    const int bb = pc>>18, z = (pc>>12)&63, y = (pc>>6)&63, x = pc&63;
    const int linb = bb << 18;
    const int az[3] = { max(z-1,0)<<12, z<<12, min(z+1,DDIM-1)<<12 };
    const int ay[3] = { max(y-1,0)<<6,  y<<6,  min(y+1,DDIM-1)<<6 };
    const int ax[3] = { max(x-1,0),     x,     min(x+1,DDIM-1) };

    floatx4 acc0 = {0.f,0.f,0.f,0.f};
    floatx4 acc1 = {0.f,0.f,0.f,0.f};

    int srcs[27];
#pragma unroll
    for (int j = 0; j < 27; ++j) {
      const int jz = j/9, jy = (j/3)%3, jx = j%3;
      const int s = map[linb | az[jz] | ay[jy] | ax[jx]];
      srcs[j] = (s < 0) ? (NPTS*CCH) : (s*CCH);   // empty voxel -> zero row
    }
#pragma unroll
    for (int j = 0; j < 27; ++j) {
      const int jz = j/9, jy = (j/3)%3, jx = j%3;
      const int tz = (cz==1) ? (2-jz) : ((jz==1) ? 1 : ((cz==0) ? 0 : 2));
      const int ty = (cy==1) ? (2-jy) : ((jy==1) ? 1 : ((cy==0) ? 0 : 2));
      const int tx = (cx==1) ? (2-jx) : ((jx==1) ? 1 : ((cx==0) ? 0 : 2));
      const int t  = tz*9 + ty*3 + tx;
      half8 a  = *(const half8*)(A + srcs[j] + quad*8);
      const _Float16* wr = sh.lw + t*(CCH*CCH);
      half8 b0 = *(const half8*)(wr + m*CCH + quad*8);
      half8 b1 = *(const half8*)(wr + (16+m)*CCH + quad*8);
      acc0 = __builtin_amdgcn_mfma_f32_16x16x32_f16(a, b0, acc0, 0, 0, 0);
      acc1 = __builtin_amdgcn_mfma_f32_16x16x32_f16(a, b1, acc1, 0, 0, 0);
    }

    // D layout: col(N=cout) = lane&15, row(M=point) = quad*4 + reg
#pragma unroll
    for (int reg = 0; reg < 4; ++reg) {
      const int r  = quad*4 + reg;
      const int pr = sorted[tile*16 + r];
      if (pr >= NPTS) continue;            // padded lane
      const float mk = mask[pr];
      float v0 = (acc0[reg] + mk*bi0) * mk;
      float v1 = (acc1[reg] + mk*bi1) * mk;
      if (MODE == 0) {
        v0 = fmaxf(v0, 0.f); v1 = fmaxf(v1, 0.f);
        hout[pr*CCH + m]      = (_Float16)v0;
        hout[pr*CCH + m + 16] = (_Float16)v1;
      } else {
        fout[pr*CCH + m]      = resid[pr*CCH + m]      + v0;
        fout[pr*CCH + m + 16] = resid[pr*CCH + m + 16] + v1;
      }
    }
  }
}

__global__ __launch_bounds__(1024, 4) void mega2(
    const float* __restrict__ values, const int* __restrict__ idx,
    const float* __restrict__ maskv,
    const float* __restrict__ k1, const float* __restrict__ bias1,
    const float* __restrict__ k2, const float* __restrict__ bias2,
    int* __restrict__ map, int* __restrict__ pcoord,
    int* __restrict__ sorted, int* __restrict__ cnt, int* __restrict__ slot,
    _Float16* __restrict__ valsh, _Float16* __restrict__ hh,
    _Float16* __restrict__ wt1, _Float16* __restrict__ wt2,
    float* __restrict__ out)
{
  __shared__ SharedC sh;
  cg::grid_group grid = cg::this_grid();
  const int gtid = blockIdx.x*NTHREADS + threadIdx.x;

  // ---- P0: init + dtype conversion (grid-stride) ----
  for (int t0 = gtid; t0 < P0N; t0 += TTOT) {
    int tid = t0;
    if (tid < GVOX/4) { ((int4*)map)[tid] = make_int4(-1,-1,-1,-1); continue; }
    tid -= GVOX/4;
    if (tid < MAXTILES*16) { sorted[tid] = NPTS; continue; }
    tid -= MAXTILES*16;
    if (tid < (NPTS*CCH)/4) {
      float4 v = ((const float4*)values)[tid];
      half4v h = { (_Float16)v.x, (_Float16)v.y, (_Float16)v.z, (_Float16)v.w };
      ((half4v*)valsh)[tid] = h; continue;
    }
    tid -= (NPTS*CCH)/4;
    if (tid < 27*CCH*CCH) {                // (t,cin,cout) f32 -> (t,cout,cin) f16
      int t = tid/(CCH*CCH), r = tid%(CCH*CCH);
      int cin = r/CCH, cout = r%CCH;
      int o = (t*CCH + cout)*CCH + cin;
      wt1[o] = (_Float16)k1[tid]; wt2[o] = (_Float16)k2[tid]; continue;
    }
    tid -= 27*CCH*CCH;
    if (tid < CCH) { valsh[NPTS*CCH+tid] = (_Float16)0.f; hh[NPTS*CCH+tid] = (_Float16)0.f; continue; }
    tid -= CCH;
    if (tid < 27) { cnt[tid] = 0; slot[tid] = 0; continue; }
    tid -= 27;
    if (tid == 0) pcoord[NPTS] = 0;        // sentinel point coords
  }
  grid.sync();

  // ---- P1: map + pcoord + class histogram ----
  if (threadIdx.x < 27) sh.lcnt[threadIdx.x] = 0;
  __syncthreads();
  int myc = -1;
  if (gtid < NPTS) {
    const int4 v = ((const int4*)idx)[gtid];
    const int b = v.x, z = v.y, y = v.z, x = v.w;
    map[((b*DDIM + z)*DDIM + y)*DDIM + x] = gtid;
    pcoord[gtid] = (b<<18) | (z<<12) | (y<<6) | x;
    const int cz = (z==0)?0:((z==DDIM-1)?2:1);
    const int cy = (y==0)?0:((y==DDIM-1)?2:1);
    const int cx = (x==0)?0:((x==DDIM-1)?2:1);
    myc = cz*9 + cy*3 + cx;
    atomicAdd(&sh.lcnt[myc], 1);
  }
  __syncthreads();
  if (threadIdx.x < 27 && sh.lcnt[threadIdx.x])
    atomicAdd(&cnt[threadIdx.x], sh.lcnt[threadIdx.x]);
  grid.sync();

  // ---- P2: per-block class scan (coherent atomic reads) + scatter ----
  if (threadIdx.x == 0) {
    int b = 0, tb = 0;
    for (int c = 0; c < 27; ++c) {
      const int cv = atomicAdd(&cnt[c], 0);   // device-coherent read
      sh.clsbase[c] = b; sh.tstart[c] = tb;
      const int ntc = (cv + 15) >> 4;
      b += ntc << 4; tb += ntc;
    }
    sh.tstart[27] = tb;
  }
  if (threadIdx.x < 27) sh.lcnt[threadIdx.x] = 0;
  __syncthreads();
  int lrank = 0;
  if (gtid < NPTS) lrank = atomicAdd(&sh.lcnt[myc], 1);
  __syncthreads();
  if (threadIdx.x < 27)
    sh.lbase[threadIdx.x] = sh.lcnt[threadIdx.x] ? atomicAdd(&slot[threadIdx.x], sh.lcnt[threadIdx.x]) : 0;
  __syncthreads();
  if (gtid < NPTS) sorted[sh.clsbase[myc] + sh.lbase[myc] + lrank] = gtid;
  grid.sync();

  // ---- P3: conv1 (relu) ----
  conv_phase_c<0>(sh, valsh, map, pcoord, sorted, wt1, bias1, maskv, nullptr, hh, nullptr);
  grid.sync();

  // ---- P4: conv2 (+residual) ----
  conv_phase_c<1>(sh, hh, map, pcoord, sorted, wt2, bias2, maskv, values, nullptr, out);
}

// ============================================================================
// Fallback path: round-4 multi-kernel pipeline (verified, 141 us)
// ============================================================================
__global__ __launch_bounds__(256) void k_prep0(
    int* __restrict__ map, int* __restrict__ sorted,
    const float* __restrict__ values, _Float16* __restrict__ valsh,
    const float* __restrict__ k1, const float* __restrict__ k2,
    _Float16* __restrict__ w1, _Float16* __restrict__ w2,
    _Float16* __restrict__ hh, int* __restrict__ pcoord,
    int* __restrict__ cnt, int* __restrict__ slot)
{
  int tid = blockIdx.x * 256 + threadIdx.x;
  if (tid < GVOX/4) { ((int4*)map)[tid] = make_int4(-1,-1,-1,-1); return; }
  tid -= GVOX/4;
  if (tid < MAXTILES*16) { sorted[tid] = NPTS; return; }
  tid -= MAXTILES*16;
  if (tid < (NPTS*CCH)/4) {
    float4 v = ((const float4*)values)[tid];
    half4v h = { (_Float16)v.x, (_Float16)v.y, (_Float16)v.z, (_Float16)v.w };
    ((half4v*)valsh)[tid] = h; return;
  }
  tid -= (NPTS*CCH)/4;
  if (tid < 27*CCH*CCH) {
    int t = tid/(CCH*CCH), r = tid%(CCH*CCH);
    int cin = r/CCH, cout = r%CCH;
    int o = (t*CCH + cout)*CCH + cin;
    w1[o] = (_Float16)k1[tid]; w2[o] = (_Float16)k2[tid]; return;
  }
  tid -= 27*CCH*CCH;
  if (tid < CCH) { valsh[NPTS*CCH+tid] = (_Float16)0.f; hh[NPTS*CCH+tid] = (_Float16)0.f; return; }
  tid -= CCH;
  if (tid < 27) { cnt[tid] = 0; slot[tid] = 0; return; }
  tid -= 27;
  if (tid == 0) pcoord[NPTS] = 0;
}

__global__ __launch_bounds__(256) void k_prep1(const int* __restrict__ idx,
                                               int* __restrict__ map,
                                               int* __restrict__ pcoord,
                                               int* __restrict__ cls,
                                               int* __restrict__ cnt)
{
  __shared__ int lcnt[27];
  if (threadIdx.x < 27) lcnt[threadIdx.x] = 0;
  __syncthreads();
  const int n = blockIdx.x*256 + threadIdx.x;
  const int4 v = ((const int4*)idx)[n];
  const int b = v.x, z = v.y, y = v.z, x = v.w;
  map[((b*DDIM + z)*DDIM + y)*DDIM + x] = n;
  pcoord[n] = (b<<18) | (z<<12) | (y<<6) | x;
  const int cz = (z==0)?0:((z==DDIM-1)?2:1);
  const int cy = (y==0)?0:((y==DDIM-1)?2:1);
  const int cx = (x==0)?0:((x==DDIM-1)?2:1);
  const int c = cz*9 + cy*3 + cx;
  cls[n] = c;
  atomicAdd(&lcnt[c], 1);
  __syncthreads();
  if (threadIdx.x < 27 && lcnt[threadIdx.x]) atomicAdd(&cnt[threadIdx.x], lcnt[threadIdx.x]);
}

__global__ __launch_bounds__(256) void k_prep3(const int* __restrict__ cls,
                                               const int* __restrict__ cnt,
                                               int* __restrict__ slot,
                                               int* __restrict__ sorted,
                                               int* __restrict__ tileclass,
                                               int* __restrict__ ntiles)
{
  __shared__ int s_clsbase[27];
  __shared__ int s_tstart[28];
  if (threadIdx.x == 0) {
    int b = 0, tb = 0;
#pragma unroll
    for (int c = 0; c < 27; ++c) {
      s_clsbase[c] = b; s_tstart[c] = tb;
      const int ntc = (cnt[c] + 15) >> 4;
      b += ntc << 4; tb += ntc;
    }
    s_tstart[27] = tb;
    if (blockIdx.x == 0) *ntiles = tb;
  }
  __syncthreads();

  if (blockIdx.x < NPTS/256) {
    __shared__ int lcnt[27], lbase[27];
    if (threadIdx.x < 27) lcnt[threadIdx.x] = 0;
    __syncthreads();
    const int n = blockIdx.x*256 + threadIdx.x;
    const int c = cls[n];
    const int lrank = atomicAdd(&lcnt[c], 1);
    __syncthreads();
    if (threadIdx.x < 27)
      lbase[threadIdx.x] = lcnt[threadIdx.x] ? atomicAdd(&slot[threadIdx.x], lcnt[threadIdx.x]) : 0;
    __syncthreads();
    sorted[s_clsbase[c] + lbase[c] + lrank] = n;
  } else {
    const int i = (blockIdx.x - NPTS/256)*256 + threadIdx.x;
    if (i >= MAXTILES) return;
    const int nt = s_tstart[27];
    int c = 13;
    if (i < nt) {
      for (int cc = 0; cc < 27; ++cc)
        if (i >= s_tstart[cc] && i < s_tstart[cc+1]) { c = cc; break; }
    }
    tileclass[i] = c;
  }
}

template<int J0, int J1>
__device__ __forceinline__ void accum_taps(
    const _Float16* __restrict__ A, const int* __restrict__ map,
    const _Float16* lw,
    int cz, int cy, int cx, int linb,
    const int* az, const int* ay, const int* ax,
    int m, int quad, floatx4& acc0, floatx4& acc1)
{
  int srcs[J1 - J0];
#pragma unroll
  for (int j = J0; j < J1; ++j) {
    const int jz = j/9, jy = (j/3)%3, jx = j%3;
    const int s = map[linb | az[jz] | ay[jy] | ax[jx]];
    srcs[j - J0] = (s < 0) ? (NPTS*CCH) : (s*CCH);
  }
#pragma unroll
  for (int j = J0; j < J1; ++j) {
    const int jz = j/9, jy = (j/3)%3, jx = j%3;
    const int tz = (cz==1) ? (2-jz) : ((jz==1) ? 1 : ((cz==0) ? 0 : 2));
    const int ty = (cy==1) ? (2-jy) : ((jy==1) ? 1 : ((cy==0) ? 0 : 2));
    const int tx = (cx==1) ? (2-jx) : ((jx==1) ? 1 : ((cx==0) ? 0 : 2));
    const int t  = tz*9 + ty*3 + tx;
    half8 a  = *(const half8*)(A + srcs[j - J0] + quad*8);
    const _Float16* wr = lw + t*(CCH*CCH);
    half8 b0 = *(const half8*)(wr + m*CCH + quad*8);
    half8 b1 = *(const half8*)(wr + (16+m)*CCH + quad*8);
    acc0 = __builtin_amdgcn_mfma_f32_16x16x32_f16(a, b0, acc0, 0, 0, 0);
    acc1 = __builtin_amdgcn_mfma_f32_16x16x32_f16(a, b1, acc1, 0, 0, 0);
  }
}

template<int MODE>
__global__ __launch_bounds__(512) void conv_mfma(
    const _Float16* __restrict__ A,
    const int* __restrict__ map,
    const int* __restrict__ pcoord,
    const int* __restrict__ sorted,
    const int* __restrict__ tileclass,
    const int* __restrict__ ntp,
    const _Float16* __restrict__ WT,
    const float* __restrict__ bias,
    const float* __restrict__ mask,
    const float* __restrict__ resid,
    _Float16* __restrict__ hout,
    float* __restrict__ fout)
{
  __shared__ _Float16 lw[27*CCH*CCH];
  __shared__ float red[4][16][33];

  for (int i = threadIdx.x; i < 3456; i += 512)
    ((half8*)lw)[i] = ((const half8*)WT)[i];

  const int wv   = threadIdx.x >> 6;
  const int tl   = wv >> 1;
  const int half = wv & 1;
  const int tile = blockIdx.x*4 + tl;
  const int nt   = *ntp;
  const bool active = tile < nt;
  const int lane = threadIdx.x & 63;
  const int m = lane & 15, quad = lane >> 4;

  floatx4 acc0 = {0.f,0.f,0.f,0.f};
  floatx4 acc1 = {0.f,0.f,0.f,0.f};

  int scls = 13, pc = 0;
  if (active) {
    scls = __builtin_amdgcn_readfirstlane(tileclass[tile]);
    const int pid = sorted[tile*16 + m];
    pc = pcoord[pid];
  }
  __syncthreads();

  if (active) {
    const int cz = scls/9, cy = (scls/3)%3, cx = scls%3;
    const int bb = pc>>18, z = (pc>>12)&63, y = (pc>>6)&63, x = pc&63;
    const int linb = bb << 18;
    const int az[3] = { max(z-1,0)<<12, z<<12, min(z+1,DDIM-1)<<12 };
    const int ay[3] = { max(y-1,0)<<6,  y<<6,  min(y+1,DDIM-1)<<6 };
    const int ax[3] = { max(x-1,0),     x,     min(x+1,DDIM-1) };
    if (half == 0)
      accum_taps<0,14>(A, map, lw, cz,cy,cx, linb, az,ay,ax, m,quad, acc0,acc1);
    else
      accum_taps<14,27>(A, map, lw, cz,cy,cx, linb, az,ay,ax, m,quad, acc0,acc1);
  }

  if (active && half == 0) {
#pragma unroll
    for (int r = 0; r < 4; ++r) {
      red[tl][quad*4+r][m]    = acc0[r];
      red[tl][quad*4+r][m+16] = acc1[r];
    }
  }
  __syncthreads();
  if (active && half == 1) {
#pragma unroll
    for (int r = 0; r < 4; ++r) {
      acc0[r] += red[tl][quad*4+r][m];
      acc1[r] += red[tl][quad*4+r][m+16];
    }
    const float bi0 = bias[m], bi1 = bias[m+16];
#pragma unroll
    for (int reg = 0; reg < 4; ++reg) {
      const int r  = quad*4 + reg;
      const int pr = sorted[tile*16 + r];
      if (pr >= NPTS) continue;
      const float mk = mask[pr];
      float v0 = (acc0[reg] + mk*bi0) * mk;
      float v1 = (acc1[reg] + mk*bi1) * mk;
      if (MODE == 0) {
        v0 = fmaxf(v0, 0.f); v1 = fmaxf(v1, 0.f);
        hout[pr*CCH + m]      = (_Float16)v0;
        hout[pr*CCH + m + 16] = (_Float16)v1;
      } else {
        fout[pr*CCH + m]      = resid[pr*CCH + m]      + v0;
        fout[pr*CCH + m + 16] = resid[pr*CCH + m + 16] + v1;
      }
    }
  }
}

// ---------------- launch ----------------

extern "C" void kernel_launch(void* const* d_in, const int* in_sizes, int n_in,
                              void* d_out, int out_size, void* d_ws, size_t ws_size,
                              hipStream_t stream) {
  const float* values = (const float*)d_in[0];
  const int*   indices= (const int*)  d_in[1];
  const float* maskv  = (const float*)d_in[2];
  const float* kern1  = (const float*)d_in[3];
  const float* bias1  = (const float*)d_in[4];
  const float* kern2  = (const float*)d_in[5];
  const float* bias2  = (const float*)d_in[6];
  float* out = (float*)d_out;

  char* ws = (char*)d_ws;
  size_t off = 0;
  auto alloc = [&](size_t bytes) { void* p = ws + off; off = (off + bytes + 255) & ~(size_t)255; return p; };
  int*      map      = (int*)     alloc(GVOX*4);            // 1 MB
  int*      pcoord   = (int*)     alloc((NPTS+1)*4);
  int*      cls      = (int*)     alloc(NPTS*4);
  int*      sorted   = (int*)     alloc(MAXTILES*16*4);
  int*      tileclass= (int*)     alloc(MAXTILES*4);
  int*      cnt      = (int*)     alloc(27*4);
  int*      slot     = (int*)     alloc(27*4);
  int*      ntiles   = (int*)     alloc(4);
  _Float16* valsh    = (_Float16*)alloc((NPTS+1)*CCH*2);    // 4 MB
  _Float16* hh       = (_Float16*)alloc((NPTS+1)*CCH*2);    // 4 MB
  _Float16* wt1      = (_Float16*)alloc(27*CCH*CCH*2);
  _Float16* wt2      = (_Float16*)alloc(27*CCH*CCH*2);

  static int use_coop = -1;
  if (use_coop < 0) {
    int nb = 0;
    hipError_t e = hipOccupancyMaxActiveBlocksPerMultiprocessor(
        &nb, (const void*)mega2, NTHREADS, 0);
    use_coop = (e == hipSuccess && nb >= 1) ? 1 : 0;
  }

  if (use_coop) {
    void* args[] = { (void*)&values, (void*)&indices, (void*)&maskv,
                     (void*)&kern1, (void*)&bias1, (void*)&kern2, (void*)&bias2,
                     (void*)&map, (void*)&pcoord, (void*)&sorted,
                     (void*)&cnt, (void*)&slot,
                     (void*)&valsh, (void*)&hh, (void*)&wt1, (void*)&wt2,
                     (void*)&out };
    hipError_t e = hipLaunchCooperativeKernel((void*)mega2, dim3(NBLOCKS),
                                              dim3(NTHREADS), args, 0, stream);
    if (e == hipSuccess) return;
    use_coop = 0;   // fall through to the verified multi-kernel path
  }

  k_prep0<<<((GVOX/4 + MAXTILES*16 + (NPTS*CCH)/4 + 27*CCH*CCH + CCH + 27 + 1) + 255)/256,
            256, 0, stream>>>(
      map, sorted, values, valsh, kern1, kern2, wt1, wt2, hh, pcoord, cnt, slot);
  k_prep1<<<NPTS/256, 256, 0, stream>>>(indices, map, pcoord, cls, cnt);
  k_prep3<<<NPTS/256 + (MAXTILES+255)/256, 256, 0, stream>>>(
      cls, cnt, slot, sorted, tileclass, ntiles);
  conv_mfma<0><<<MAXTILES/4, 512, 0, stream>>>(valsh, map, pcoord, sorted, tileclass,
                                               ntiles, wt1, bias1, maskv, nullptr, hh, nullptr);
  conv_mfma<1><<<MAXTILES/4, 512, 0, stream>>>(hh, map, pcoord, sorted, tileclass,
                                               ntiles, wt2, bias2, maskv, values, nullptr, out);
}

// Round 8
// 128.626 us; speedup vs baseline: 1.4787x; 1.0913x over previous
//
#include <hip/hip_runtime.h>

#define NPTS 65536
#define CCH  32
#define DDIM 64
#define GVOX (DDIM*DDIM*DDIM)   // B=1 -> 262144 voxels
#define MAXTILES 4128           // >= 65536/16 + 27 (per-class padding)
#define NSLOT (MAXTILES*16)

typedef _Float16 half8  __attribute__((ext_vector_type(8)));
typedef _Float16 half4v __attribute__((ext_vector_type(4)));
typedef float    floatx4 __attribute__((ext_vector_type(4)));

// ---------------- prep0: init + dtype conversion (one launch) ----------------
// ranges: map | sorted | pcs | values->f16 | weight transpose(permuted) | zero rows | counters
__global__ __launch_bounds__(256) void k_prep0(
    int* __restrict__ map, int* __restrict__ sorted, int* __restrict__ pcs,
    const float* __restrict__ values, _Float16* __restrict__ valsh,
    const float* __restrict__ k1, const float* __restrict__ k2,
    _Float16* __restrict__ w1, _Float16* __restrict__ w2,
    _Float16* __restrict__ hh, int* __restrict__ pcoord,
    int* __restrict__ cnt, int* __restrict__ slot)
{
  int tid = blockIdx.x * 256 + threadIdx.x;
  if (tid < GVOX/4) { ((int4*)map)[tid] = make_int4(-1,-1,-1,-1); return; }
  tid -= GVOX/4;
  if (tid < NSLOT) { sorted[tid] = NPTS; return; }
  tid -= NSLOT;
  if (tid < NSLOT) { pcs[tid] = 0; return; }
  tid -= NSLOT;
  if (tid < (NPTS*CCH)/4) {
    float4 v = ((const float4*)values)[tid];
    half4v h = { (_Float16)v.x, (_Float16)v.y, (_Float16)v.z, (_Float16)v.w };
    ((half4v*)valsh)[tid] = h; return;
  }
  tid -= (NPTS*CCH)/4;
  if (tid < 27*CCH*CCH) {
    // (t,cin,cout) f32 -> lane-linear f16 layout:
    // chunk for MFMA-lane l=(q*16+m) of half h=(cout>>4) at t*1024 + h*512 + l*8 + i
    int t = tid/(CCH*CCH), r = tid%(CCH*CCH);
    int cin = r/CCH, cout = r%CCH;
    int h = cout >> 4, mm = cout & 15, q = cin >> 3, i = cin & 7;
    int o = t*1024 + h*512 + (q*16 + mm)*8 + i;
    w1[o] = (_Float16)k1[tid]; w2[o] = (_Float16)k2[tid]; return;
  }
  tid -= 27*CCH*CCH;
  if (tid < CCH) { valsh[NPTS*CCH+tid] = (_Float16)0.f; hh[NPTS*CCH+tid] = (_Float16)0.f; return; }
  tid -= CCH;
  if (tid < 27) { cnt[tid] = 0; slot[tid] = 0; return; }
  tid -= 27;
  if (tid == 0) pcoord[NPTS] = 0;
}
#define PREP0_THREADS (GVOX/4 + NSLOT + NSLOT + (NPTS*CCH)/4 + 27*CCH*CCH + CCH + 27 + 1)

// ---------------- prep1: map + pcoord + class histogram ----------------
__global__ __launch_bounds__(256) void k_prep1(const int* __restrict__ idx,
                                               int* __restrict__ map,
                                               int* __restrict__ pcoord,
                                               int* __restrict__ cls,
                                               int* __restrict__ cnt)
{
  __shared__ int lcnt[27];
  if (threadIdx.x < 27) lcnt[threadIdx.x] = 0;
  __syncthreads();
  const int n = blockIdx.x*256 + threadIdx.x;
  const int4 v = ((const int4*)idx)[n];
  const int b = v.x, z = v.y, y = v.z, x = v.w;
  map[((b*DDIM + z)*DDIM + y)*DDIM + x] = n;
  pcoord[n] = (b<<18) | (z<<12) | (y<<6) | x;
  const int cz = (z==0)?0:((z==DDIM-1)?2:1);
  const int cy = (y==0)?0:((y==DDIM-1)?2:1);
  const int cx = (x==0)?0:((x==DDIM-1)?2:1);
  const int c = cz*9 + cy*3 + cx;
  cls[n] = c;
  atomicAdd(&lcnt[c], 1);
  __syncthreads();
  if (threadIdx.x < 27 && lcnt[threadIdx.x]) atomicAdd(&cnt[threadIdx.x], lcnt[threadIdx.x]);
}

// ---------------- prep3: per-block 27-class scan + scatter (+pcs) + tileclass
__global__ __launch_bounds__(256) void k_prep3(const int* __restrict__ cls,
                                               const int* __restrict__ cnt,
                                               int* __restrict__ slot,
                                               const int* __restrict__ pcoord,
                                               int* __restrict__ sorted,
                                               int* __restrict__ pcs,
                                               int* __restrict__ tileclass,
                                               int* __restrict__ ntiles)
{
  __shared__ int s_clsbase[27];
  __shared__ int s_tstart[28];
  if (threadIdx.x == 0) {
    int b = 0, tb = 0;
#pragma unroll
    for (int c = 0; c < 27; ++c) {
      s_clsbase[c] = b; s_tstart[c] = tb;
      const int ntc = (cnt[c] + 15) >> 4;
      b += ntc << 4; tb += ntc;
    }
    s_tstart[27] = tb;
    if (blockIdx.x == 0) *ntiles = tb;
  }
  __syncthreads();

  if (blockIdx.x < NPTS/256) {
    __shared__ int lcnt[27], lbase[27];
    if (threadIdx.x < 27) lcnt[threadIdx.x] = 0;
    __syncthreads();
    const int n = blockIdx.x*256 + threadIdx.x;
    const int c = cls[n];
    const int lrank = atomicAdd(&lcnt[c], 1);
    __syncthreads();
    if (threadIdx.x < 27)
      lbase[threadIdx.x] = lcnt[threadIdx.x] ? atomicAdd(&slot[threadIdx.x], lcnt[threadIdx.x]) : 0;
    __syncthreads();
    const int s = s_clsbase[c] + lbase[c] + lrank;
    sorted[s] = n;
    pcs[s] = pcoord[n];
  } else {
    const int i = (blockIdx.x - NPTS/256)*256 + threadIdx.x;
    if (i >= MAXTILES) return;
    const int nt = s_tstart[27];
    int c = 13;
    if (i < nt) {
      for (int cc = 0; cc < 27; ++cc)
        if (i >= s_tstart[cc] && i < s_tstart[cc+1]) { c = cc; break; }
    }
    tileclass[i] = c;
  }
}

// ---------------- k_nbr: resolve all 27 neighbor A-offsets per slot ----------
// Layout nbr[(tile*27 + j)*16 + m] -> one 64B line per (tile, tap).
// Computed once, used by BOTH convs (removes the map-gather chain from conv).
__global__ __launch_bounds__(256) void k_nbr(const int* __restrict__ pcs,
                                             const int* __restrict__ map,
                                             int* __restrict__ nbr)
{
  const int tid = blockIdx.x*256 + threadIdx.x;
  if (tid >= MAXTILES*432) return;
  const int tile = tid/432, rem = tid%432;
  const int j = rem >> 4, m = rem & 15;
  const int pc = pcs[tile*16 + m];
  const int bb = pc>>18, z = (pc>>12)&63, y = (pc>>6)&63, x = pc&63;
  const int jz = j/9, jy = (j/3)%3, jx = j%3;
  const int nz = min(max(z + jz - 1, 0), DDIM-1);
  const int ny = min(max(y + jy - 1, 0), DDIM-1);
  const int nx = min(max(x + jx - 1, 0), DDIM-1);
  const int s = map[(bb<<18) | (nz<<12) | (ny<<6) | nx];
  nbr[tid] = ((s < 0) ? NPTS : s) * CCH;
}

// ---------------- conv: nbr-driven gather + grouped A-prefetch + MFMA --------
template<int MODE>
__global__ __launch_bounds__(512, 4) void conv_mfma(
    const _Float16* __restrict__ A,        // (NPTS+1) x 32 f16, row NPTS = zeros
    const int* __restrict__ nbr,
    const int* __restrict__ sorted,
    const int* __restrict__ tileclass,
    const int* __restrict__ ntp,
    const _Float16* __restrict__ WT,       // 27 x 1024 f16, lane-linear layout
    const float* __restrict__ bias,
    const float* __restrict__ mask,
    const float* __restrict__ resid,
    _Float16* __restrict__ hout,
    float* __restrict__ fout)
{
  __shared__ _Float16 lw[27*CCH*CCH];      // 55296 B, linear copy of WT
  for (int i = threadIdx.x; i < 3456; i += 512)
    ((half8*)lw)[i] = ((const half8*)WT)[i];
  __syncthreads();

  const int wv   = threadIdx.x >> 6;       // 0..7, wave = 1 tile
  const int tile = blockIdx.x*8 + wv;
  const int lane = threadIdx.x & 63;
  const int m = lane & 15, quad = lane >> 4;
  if (tile >= *ntp) return;

  const int scls = __builtin_amdgcn_readfirstlane(tileclass[tile]);
  const int cz = scls/9, cy = (scls/3)%3, cx = scls%3;

  // all 27 A-row offsets: contiguous 1.7KB block, 27 independent 1-line loads
  const int tb = tile*432;
  int srcs[27];
#pragma unroll
  for (int j = 0; j < 27; ++j) srcs[j] = nbr[tb + j*16 + m];

  floatx4 acc0 = {0.f,0.f,0.f,0.f};
  floatx4 acc1 = {0.f,0.f,0.f,0.f};

#pragma unroll
  for (int g = 0; g < 3; ++g) {
    half8 av[9];
#pragma unroll
    for (int u = 0; u < 9; ++u)            // 9 independent gathers in flight
      av[u] = *(const half8*)(A + srcs[g*9 + u] + quad*8);
#pragma unroll
    for (int u = 0; u < 9; ++u) {
      const int j = g*9 + u;
      const int jz = j/9, jy = (j/3)%3, jx = j%3;
      const int tz = (cz==1) ? (2-jz) : ((jz==1) ? 1 : ((cz==0) ? 0 : 2));
      const int ty = (cy==1) ? (2-jy) : ((jy==1) ? 1 : ((cy==0) ? 0 : 2));
      const int tx = (cx==1) ? (2-jx) : ((jx==1) ? 1 : ((cx==0) ? 0 : 2));
      const int t  = tz*9 + ty*3 + tx;
      const _Float16* wr = lw + t*1024;    // lane-linear: lane l -> byte l*16
      half8 b0 = *(const half8*)(wr + lane*8);
      half8 b1 = *(const half8*)(wr + 512 + lane*8);
      acc0 = __builtin_amdgcn_mfma_f32_16x16x32_f16(av[u], b0, acc0, 0, 0, 0);
      acc1 = __builtin_amdgcn_mfma_f32_16x16x32_f16(av[u], b1, acc1, 0, 0, 0);
    }
  }

  // D layout: col(N=cout) = lane&15, row(M=point) = quad*4 + reg
  const float bi0 = bias[m], bi1 = bias[m+16];
#pragma unroll
  for (int reg = 0; reg < 4; ++reg) {
    const int r  = quad*4 + reg;
    const int pr = sorted[tile*16 + r];
    if (pr >= NPTS) continue;              // padded lane
    const float mk = mask[pr];
    float v0 = (acc0[reg] + mk*bi0) * mk;
    float v1 = (acc1[reg] + mk*bi1) * mk;
    if (MODE == 0) {
      v0 = fmaxf(v0, 0.f); v1 = fmaxf(v1, 0.f);
      hout[pr*CCH + m]      = (_Float16)v0;
      hout[pr*CCH + m + 16] = (_Float16)v1;
    } else {
      fout[pr*CCH + m]      = resid[pr*CCH + m]      + v0;
      fout[pr*CCH + m + 16] = resid[pr*CCH + m + 16] + v1;
    }
  }
}

// ---------------- launch ----------------

extern "C" void kernel_launch(void* const* d_in, const int* in_sizes, int n_in,
                              void* d_out, int out_size, void* d_ws, size_t ws_size,
                              hipStream_t stream) {
  const float* values = (const float*)d_in[0];
  const int*   indices= (const int*)  d_in[1];
  const float* maskv  = (const float*)d_in[2];
  const float* kern1  = (const float*)d_in[3];
  const float* bias1  = (const float*)d_in[4];
  const float* kern2  = (const float*)d_in[5];
  const float* bias2  = (const float*)d_in[6];
  float* out = (float*)d_out;

  char* ws = (char*)d_ws;
  size_t off = 0;
  auto alloc = [&](size_t bytes) { void* p = ws + off; off = (off + bytes + 255) & ~(size_t)255; return p; };
  int*      map      = (int*)     alloc(GVOX*4);            // 1 MB
  int*      pcoord   = (int*)     alloc((NPTS+1)*4);
  int*      cls      = (int*)     alloc(NPTS*4);
  int*      sorted   = (int*)     alloc(NSLOT*4);
  int*      pcs      = (int*)     alloc(NSLOT*4);
  int*      tileclass= (int*)     alloc(MAXTILES*4);
  int*      nbr      = (int*)     alloc((size_t)MAXTILES*432*4);  // ~7 MB
  int*      cnt      = (int*)     alloc(27*4);
  int*      slot     = (int*)     alloc(27*4);
  int*      ntiles   = (int*)     alloc(4);
  _Float16* valsh    = (_Float16*)alloc((NPTS+1)*CCH*2);    // 4 MB
  _Float16* hh       = (_Float16*)alloc((NPTS+1)*CCH*2);    // 4 MB
  _Float16* wt1      = (_Float16*)alloc(27*CCH*CCH*2);
  _Float16* wt2      = (_Float16*)alloc(27*CCH*CCH*2);

  k_prep0<<<(PREP0_THREADS + 255)/256, 256, 0, stream>>>(
      map, sorted, pcs, values, valsh, kern1, kern2, wt1, wt2, hh, pcoord, cnt, slot);
  k_prep1<<<NPTS/256, 256, 0, stream>>>(indices, map, pcoord, cls, cnt);
  k_prep3<<<NPTS/256 + (MAXTILES+255)/256, 256, 0, stream>>>(
      cls, cnt, slot, pcoord, sorted, pcs, tileclass, ntiles);
  k_nbr<<<(MAXTILES*432 + 255)/256, 256, 0, stream>>>(pcs, map, nbr);

  conv_mfma<0><<<(MAXTILES + 7)/8, 512, 0, stream>>>(valsh, nbr, sorted, tileclass,
                                                     ntiles, wt1, bias1, maskv, nullptr, hh, nullptr);
  conv_mfma<1><<<(MAXTILES + 7)/8, 512, 0, stream>>>(hh, nbr, sorted, tileclass,
                                                     ntiles, wt2, bias2, maskv, values, nullptr, out);
}

// Round 9
// 128.448 us; speedup vs baseline: 1.4808x; 1.0014x over previous
//
#include <hip/hip_runtime.h>
#include <hip/hip_cooperative_groups.h>

namespace cg = cooperative_groups;

#define NPTS 65536
#define CCH  32
#define DDIM 64
#define GVOX (DDIM*DDIM*DDIM)   // B=1 -> 262144 voxels
#define MAXTILES 4128           // >= 65536/16 + 27 (per-class padding)
#define NSLOT (MAXTILES*16)
#define NTHREADS 1024
#define NBLOCKS  256
#define TTOT (NTHREADS*NBLOCKS)

typedef _Float16 half8  __attribute__((ext_vector_type(8)));
typedef _Float16 half4v __attribute__((ext_vector_type(4)));
typedef float    floatx4 __attribute__((ext_vector_type(4)));

// P0 ranges: map | sorted | pcs | values->f16 | weights | zero rows | cnt+slot
#define P0N (GVOX/4 + NSLOT/4 + NSLOT/4 + (NPTS*CCH)/4 + 27*CCH*CCH + CCH + 27)

// ============================================================================
// Fused cooperative kernel (round-8-quality conv inside)
// ============================================================================
struct SharedC {
  _Float16 lw[27*CCH*CCH];   // 55296 B: all 27 taps' weights, lane-linear
  int tstart[28];
  int clsbase[27];
  int lcnt[27];
  int lbase[27];
};

// conv phase: wave = 1 tile x 27 taps. Batched map-gather (27 independent
// loads -> srcs regs), grouped 9-wide A-prefetch, lane-linear LDS B-reads
// (conflict-free), setprio around MFMA clusters.
template<int MODE>
__device__ void conv_phase(SharedC& sh,
    const _Float16* __restrict__ A, const int* __restrict__ map,
    const int* __restrict__ pcs, const int* __restrict__ sorted,
    const _Float16* __restrict__ WT, const float* __restrict__ bias,
    const float* __restrict__ mask, const float* __restrict__ resid,
    _Float16* __restrict__ hout, float* __restrict__ fout)
{
  for (int i = threadIdx.x; i < 3456; i += NTHREADS)
    ((half8*)sh.lw)[i] = ((const half8*)WT)[i];
  __syncthreads();

  const int wv   = threadIdx.x >> 6;       // 0..15, wave = 1 tile
  const int lane = threadIdx.x & 63;
  const int m = lane & 15, quad = lane >> 4;
  const int nt = sh.tstart[27];
  const float bi0 = bias[m], bi1 = bias[m+16];

  for (int tile = blockIdx.x*16 + wv; tile < nt; tile += NBLOCKS*16) {
    int scls = 0;
    for (int cc = 1; cc < 27; ++cc) if (tile >= sh.tstart[cc]) scls = cc;
    scls = __builtin_amdgcn_readfirstlane(scls);
    const int cz = scls/9, cy = (scls/3)%3, cx = scls%3;

    const int pc = pcs[tile*16 + m];       // slot-indexed packed coords
    const int bb = pc>>18, z = (pc>>12)&63, y = (pc>>6)&63, x = pc&63;
    const int linb = bb << 18;
    const int az[3] = { max(z-1,0)<<12, z<<12, min(z+1,DDIM-1)<<12 };
    const int ay[3] = { max(y-1,0)<<6,  y<<6,  min(y+1,DDIM-1)<<6 };
    const int ax[3] = { max(x-1,0),     x,     min(x+1,DDIM-1) };

    int srcs[27];                          // 27 independent gathers, 1 round trip
#pragma unroll
    for (int j = 0; j < 27; ++j) {
      const int jz = j/9, jy = (j/3)%3, jx = j%3;
      const int s = map[linb | az[jz] | ay[jy] | ax[jx]];
      srcs[j] = ((s < 0) ? NPTS : s) * CCH;   // empty voxel -> zero row
    }

    floatx4 acc0 = {0.f,0.f,0.f,0.f};
    floatx4 acc1 = {0.f,0.f,0.f,0.f};

#pragma unroll
    for (int g = 0; g < 3; ++g) {
      half8 av[9];
#pragma unroll
      for (int u = 0; u < 9; ++u)          // 9 independent A-gathers in flight
        av[u] = *(const half8*)(A + srcs[g*9 + u] + quad*8);
      __builtin_amdgcn_s_setprio(1);
#pragma unroll
      for (int u = 0; u < 9; ++u) {
        const int j = g*9 + u;
        const int jz = j/9, jy = (j/3)%3, jx = j%3;
        const int tz = (cz==1) ? (2-jz) : ((jz==1) ? 1 : ((cz==0) ? 0 : 2));
        const int ty = (cy==1) ? (2-jy) : ((jy==1) ? 1 : ((cy==0) ? 0 : 2));
        const int tx = (cx==1) ? (2-jx) : ((jx==1) ? 1 : ((cx==0) ? 0 : 2));
        const int t  = tz*9 + ty*3 + tx;
        const _Float16* wr = sh.lw + t*1024;  // lane l -> byte l*16, linear
        half8 b0 = *(const half8*)(wr + lane*8);
        half8 b1 = *(const half8*)(wr + 512 + lane*8);
        acc0 = __builtin_amdgcn_mfma_f32_16x16x32_f16(av[u], b0, acc0, 0, 0, 0);
        acc1 = __builtin_amdgcn_mfma_f32_16x16x32_f16(av[u], b1, acc1, 0, 0, 0);
      }
      __builtin_amdgcn_s_setprio(0);
    }

    // D layout: col(N=cout) = lane&15, row(M=point) = quad*4 + reg
#pragma unroll
    for (int reg = 0; reg < 4; ++reg) {
      const int r  = quad*4 + reg;
      const int pr = sorted[tile*16 + r];
      if (pr >= NPTS) continue;            // padded lane
      const float mk = mask[pr];
      float v0 = (acc0[reg] + mk*bi0) * mk;
      float v1 = (acc1[reg] + mk*bi1) * mk;
      if (MODE == 0) {
        v0 = fmaxf(v0, 0.f); v1 = fmaxf(v1, 0.f);
        hout[pr*CCH + m]      = (_Float16)v0;
        hout[pr*CCH + m + 16] = (_Float16)v1;
      } else {
        fout[pr*CCH + m]      = resid[pr*CCH + m]      + v0;
        fout[pr*CCH + m + 16] = resid[pr*CCH + m + 16] + v1;
      }
    }
  }
}

__global__ __launch_bounds__(1024, 4) void mega3(
    const float* __restrict__ values, const int* __restrict__ idx,
    const float* __restrict__ maskv,
    const float* __restrict__ k1, const float* __restrict__ bias1,
    const float* __restrict__ k2, const float* __restrict__ bias2,
    int* __restrict__ map, int* __restrict__ sorted, int* __restrict__ pcs,
    int* __restrict__ cnt, int* __restrict__ slot,
    _Float16* __restrict__ valsh, _Float16* __restrict__ hh,
    _Float16* __restrict__ wt1, _Float16* __restrict__ wt2,
    float* __restrict__ out)
{
  __shared__ SharedC sh;
  cg::grid_group grid = cg::this_grid();
  const int gtid = blockIdx.x*NTHREADS + threadIdx.x;

  // ---- P0: init + dtype conversion (grid-stride) ----
  for (int t0 = gtid; t0 < P0N; t0 += TTOT) {
    int tid = t0;
    if (tid < GVOX/4) { ((int4*)map)[tid] = make_int4(-1,-1,-1,-1); continue; }
    tid -= GVOX/4;
    if (tid < NSLOT/4) { ((int4*)sorted)[tid] = make_int4(NPTS,NPTS,NPTS,NPTS); continue; }
    tid -= NSLOT/4;
    if (tid < NSLOT/4) { ((int4*)pcs)[tid] = make_int4(0,0,0,0); continue; }
    tid -= NSLOT/4;
    if (tid < (NPTS*CCH)/4) {
      float4 v = ((const float4*)values)[tid];
      half4v h = { (_Float16)v.x, (_Float16)v.y, (_Float16)v.z, (_Float16)v.w };
      ((half4v*)valsh)[tid] = h; continue;
    }
    tid -= (NPTS*CCH)/4;
    if (tid < 27*CCH*CCH) {
      // (t,cin,cout) f32 -> lane-linear f16: o = t*1024 + h*512 + l*8 + i
      int t = tid/(CCH*CCH), r = tid%(CCH*CCH);
      int cin = r/CCH, cout = r%CCH;
      int h = cout >> 4, mm = cout & 15, q = cin >> 3, i = cin & 7;
      int o = t*1024 + h*512 + (q*16 + mm)*8 + i;
      wt1[o] = (_Float16)k1[tid]; wt2[o] = (_Float16)k2[tid]; continue;
    }
    tid -= 27*CCH*CCH;
    if (tid < CCH) { valsh[NPTS*CCH+tid] = (_Float16)0.f; hh[NPTS*CCH+tid] = (_Float16)0.f; continue; }
    tid -= CCH;
    if (tid < 27) { cnt[tid] = 0; slot[tid] = 0; continue; }
  }
  grid.sync();

  // ---- P1: map + class histogram (pc/myc kept in registers) ----
  if (threadIdx.x < 27) sh.lcnt[threadIdx.x] = 0;
  __syncthreads();
  int myc = -1, mypc = 0;
  if (gtid < NPTS) {
    const int4 v = ((const int4*)idx)[gtid];
    const int b = v.x, z = v.y, y = v.z, x = v.w;
    map[((b*DDIM + z)*DDIM + y)*DDIM + x] = gtid;
    mypc = (b<<18) | (z<<12) | (y<<6) | x;
    const int cz = (z==0)?0:((z==DDIM-1)?2:1);
    const int cy = (y==0)?0:((y==DDIM-1)?2:1);
    const int cx = (x==0)?0:((x==DDIM-1)?2:1);
    myc = cz*9 + cy*3 + cx;
    atomicAdd(&sh.lcnt[myc], 1);
  }
  __syncthreads();
  if (threadIdx.x < 27 && sh.lcnt[threadIdx.x])
    atomicAdd(&cnt[threadIdx.x], sh.lcnt[threadIdx.x]);
  grid.sync();

  // ---- P2: per-block class scan (coherent reads) + scatter (sorted, pcs) ----
  if (threadIdx.x == 0) {
    int b = 0, tb = 0;
    for (int c = 0; c < 27; ++c) {
      const int cv = atomicAdd(&cnt[c], 0);   // device-coherent read
      sh.clsbase[c] = b; sh.tstart[c] = tb;
      const int ntc = (cv + 15) >> 4;
      b += ntc << 4; tb += ntc;
    }
    sh.tstart[27] = tb;
  }
  if (threadIdx.x < 27) sh.lcnt[threadIdx.x] = 0;
  __syncthreads();
  int lrank = 0;
  if (gtid < NPTS) lrank = atomicAdd(&sh.lcnt[myc], 1);
  __syncthreads();
  if (threadIdx.x < 27)
    sh.lbase[threadIdx.x] = sh.lcnt[threadIdx.x] ? atomicAdd(&slot[threadIdx.x], sh.lcnt[threadIdx.x]) : 0;
  __syncthreads();
  if (gtid < NPTS) {
    const int s = sh.clsbase[myc] + sh.lbase[myc] + lrank;
    sorted[s] = gtid;
    pcs[s] = mypc;
  }
  grid.sync();

  // ---- P3: conv1 (relu) ----
  conv_phase<0>(sh, valsh, map, pcs, sorted, wt1, bias1, maskv, nullptr, hh, nullptr);
  grid.sync();

  // ---- P4: conv2 (+residual) ----
  conv_phase<1>(sh, hh, map, pcs, sorted, wt2, bias2, maskv, values, nullptr, out);
}

// ============================================================================
// Fallback path: round-8 multi-kernel pipeline (verified, 128.6 us)
// ============================================================================
__global__ __launch_bounds__(256) void k_prep0(
    int* __restrict__ map, int* __restrict__ sorted, int* __restrict__ pcs,
    const float* __restrict__ values, _Float16* __restrict__ valsh,
    const float* __restrict__ k1, const float* __restrict__ k2,
    _Float16* __restrict__ w1, _Float16* __restrict__ w2,
    _Float16* __restrict__ hh, int* __restrict__ pcoord,
    int* __restrict__ cnt, int* __restrict__ slot)
{
  int tid = blockIdx.x * 256 + threadIdx.x;
  if (tid < GVOX/4) { ((int4*)map)[tid] = make_int4(-1,-1,-1,-1); return; }
  tid -= GVOX/4;
  if (tid < NSLOT) { sorted[tid] = NPTS; return; }
  tid -= NSLOT;
  if (tid < NSLOT) { pcs[tid] = 0; return; }
  tid -= NSLOT;
  if (tid < (NPTS*CCH)/4) {
    float4 v = ((const float4*)values)[tid];
    half4v h = { (_Float16)v.x, (_Float16)v.y, (_Float16)v.z, (_Float16)v.w };
    ((half4v*)valsh)[tid] = h; return;
  }
  tid -= (NPTS*CCH)/4;
  if (tid < 27*CCH*CCH) {
    int t = tid/(CCH*CCH), r = tid%(CCH*CCH);
    int cin = r/CCH, cout = r%CCH;
    int h = cout >> 4, mm = cout & 15, q = cin >> 3, i = cin & 7;
    int o = t*1024 + h*512 + (q*16 + mm)*8 + i;
    w1[o] = (_Float16)k1[tid]; w2[o] = (_Float16)k2[tid]; return;
  }
  tid -= 27*CCH*CCH;
  if (tid < CCH) { valsh[NPTS*CCH+tid] = (_Float16)0.f; hh[NPTS*CCH+tid] = (_Float16)0.f; return; }
  tid -= CCH;
  if (tid < 27) { cnt[tid] = 0; slot[tid] = 0; return; }
  tid -= 27;
  if (tid == 0) pcoord[NPTS] = 0;
}
#define PREP0_THREADS (GVOX/4 + NSLOT + NSLOT + (NPTS*CCH)/4 + 27*CCH*CCH + CCH + 27 + 1)

__global__ __launch_bounds__(256) void k_prep1(const int* __restrict__ idx,
                                               int* __restrict__ map,
                                               int* __restrict__ pcoord,
                                               int* __restrict__ cls,
                                               int* __restrict__ cnt)
{
  __shared__ int lcnt[27];
  if (threadIdx.x < 27) lcnt[threadIdx.x] = 0;
  __syncthreads();
  const int n = blockIdx.x*256 + threadIdx.x;
  const int4 v = ((const int4*)idx)[n];
  const int b = v.x, z = v.y, y = v.z, x = v.w;
  map[((b*DDIM + z)*DDIM + y)*DDIM + x] = n;
  pcoord[n] = (b<<18) | (z<<12) | (y<<6) | x;
  const int cz = (z==0)?0:((z==DDIM-1)?2:1);
  const int cy = (y==0)?0:((y==DDIM-1)?2:1);
  const int cx = (x==0)?0:((x==DDIM-1)?2:1);
  const int c = cz*9 + cy*3 + cx;
  cls[n] = c;
  atomicAdd(&lcnt[c], 1);
  __syncthreads();
  if (threadIdx.x < 27 && lcnt[threadIdx.x]) atomicAdd(&cnt[threadIdx.x], lcnt[threadIdx.x]);
}

__global__ __launch_bounds__(256) void k_prep3(const int* __restrict__ cls,
                                               const int* __restrict__ cnt,
                                               int* __restrict__ slot,
                                               const int* __restrict__ pcoord,
                                               int* __restrict__ sorted,
                                               int* __restrict__ pcs,
                                               int* __restrict__ tileclass,
                                               int* __restrict__ ntiles)
{
  __shared__ int s_clsbase[27];
  __shared__ int s_tstart[28];
  if (threadIdx.x == 0) {
    int b = 0, tb = 0;
#pragma unroll
    for (int c = 0; c < 27; ++c) {
      s_clsbase[c] = b; s_tstart[c] = tb;
      const int ntc = (cnt[c] + 15) >> 4;
      b += ntc << 4; tb += ntc;
    }
    s_tstart[27] = tb;
    if (blockIdx.x == 0) *ntiles = tb;
  }
  __syncthreads();

  if (blockIdx.x < NPTS/256) {
    __shared__ int lcnt[27], lbase[27];
    if (threadIdx.x < 27) lcnt[threadIdx.x] = 0;
    __syncthreads();
    const int n = blockIdx.x*256 + threadIdx.x;
    const int c = cls[n];
    const int lrank = atomicAdd(&lcnt[c], 1);
    __syncthreads();
    if (threadIdx.x < 27)
      lbase[threadIdx.x] = lcnt[threadIdx.x] ? atomicAdd(&slot[threadIdx.x], lcnt[threadIdx.x]) : 0;
    __syncthreads();
    const int s = s_clsbase[c] + lbase[c] + lrank;
    sorted[s] = n;
    pcs[s] = pcoord[n];
  } else {
    const int i = (blockIdx.x - NPTS/256)*256 + threadIdx.x;
    if (i >= MAXTILES) return;
    const int nt = s_tstart[27];
    int c = 13;
    if (i < nt) {
      for (int cc = 0; cc < 27; ++cc)
        if (i >= s_tstart[cc] && i < s_tstart[cc+1]) { c = cc; break; }
    }
    tileclass[i] = c;
  }
}

__global__ __launch_bounds__(256) void k_nbr(const int* __restrict__ pcs,
                                             const int* __restrict__ map,
                                             int* __restrict__ nbr)
{
  const int tid = blockIdx.x*256 + threadIdx.x;
  if (tid >= MAXTILES*432) return;
  const int tile = tid/432, rem = tid%432;
  const int j = rem >> 4, m = rem & 15;
  const int pc = pcs[tile*16 + m];
  const int bb = pc>>18, z = (pc>>12)&63, y = (pc>>6)&63, x = pc&63;
  const int jz = j/9, jy = (j/3)%3, jx = j%3;
  const int nz = min(max(z + jz - 1, 0), DDIM-1);
  const int ny = min(max(y + jy - 1, 0), DDIM-1);
  const int nx = min(max(x + jx - 1, 0), DDIM-1);
  const int s = map[(bb<<18) | (nz<<12) | (ny<<6) | nx];
  nbr[tid] = ((s < 0) ? NPTS : s) * CCH;
}

template<int MODE>
__global__ __launch_bounds__(512, 4) void conv_mfma(
    const _Float16* __restrict__ A,
    const int* __restrict__ nbr,
    const int* __restrict__ sorted,
    const int* __restrict__ tileclass,
    const int* __restrict__ ntp,
    const _Float16* __restrict__ WT,
    const float* __restrict__ bias,
    const float* __restrict__ mask,
    const float* __restrict__ resid,
    _Float16* __restrict__ hout,
    float* __restrict__ fout)
{
  __shared__ _Float16 lw[27*CCH*CCH];
  for (int i = threadIdx.x; i < 3456; i += 512)
    ((half8*)lw)[i] = ((const half8*)WT)[i];
  __syncthreads();

  const int wv   = threadIdx.x >> 6;
  const int tile = blockIdx.x*8 + wv;
  const int lane = threadIdx.x & 63;
  const int m = lane & 15, quad = lane >> 4;
  if (tile >= *ntp) return;

  const int scls = __builtin_amdgcn_readfirstlane(tileclass[tile]);
  const int cz = scls/9, cy = (scls/3)%3, cx = scls%3;

  const int tb = tile*432;
  int srcs[27];
#pragma unroll
  for (int j = 0; j < 27; ++j) srcs[j] = nbr[tb + j*16 + m];

  floatx4 acc0 = {0.f,0.f,0.f,0.f};
  floatx4 acc1 = {0.f,0.f,0.f,0.f};

#pragma unroll
  for (int g = 0; g < 3; ++g) {
    half8 av[9];
#pragma unroll
    for (int u = 0; u < 9; ++u)
      av[u] = *(const half8*)(A + srcs[g*9 + u] + quad*8);
#pragma unroll
    for (int u = 0; u < 9; ++u) {
      const int j = g*9 + u;
      const int jz = j/9, jy = (j/3)%3, jx = j%3;
      const int tz = (cz==1) ? (2-jz) : ((jz==1) ? 1 : ((cz==0) ? 0 : 2));
      const int ty = (cy==1) ? (2-jy) : ((jy==1) ? 1 : ((cy==0) ? 0 : 2));
      const int tx = (cx==1) ? (2-jx) : ((jx==1) ? 1 : ((cx==0) ? 0 : 2));
      const int t  = tz*9 + ty*3 + tx;
      const _Float16* wr = lw + t*1024;
      half8 b0 = *(const half8*)(wr + lane*8);
      half8 b1 = *(const half8*)(wr + 512 + lane*8);
      acc0 = __builtin_amdgcn_mfma_f32_16x16x32_f16(av[u], b0, acc0, 0, 0, 0);
      acc1 = __builtin_amdgcn_mfma_f32_16x16x32_f16(av[u], b1, acc1, 0, 0, 0);
    }
  }

  const float bi0 = bias[m], bi1 = bias[m+16];
#pragma unroll
  for (int reg = 0; reg < 4; ++reg) {
    const int r  = quad*4 + reg;
    const int pr = sorted[tile*16 + r];
    if (pr >= NPTS) continue;
    const float mk = mask[pr];
    float v0 = (acc0[reg] + mk*bi0) * mk;
    float v1 = (acc1[reg] + mk*bi1) * mk;
    if (MODE == 0) {
      v0 = fmaxf(v0, 0.f); v1 = fmaxf(v1, 0.f);
      hout[pr*CCH + m]      = (_Float16)v0;
      hout[pr*CCH + m + 16] = (_Float16)v1;
    } else {
      fout[pr*CCH + m]      = resid[pr*CCH + m]      + v0;
      fout[pr*CCH + m + 16] = resid[pr*CCH + m + 16] + v1;
    }
  }
}

// ---------------- launch ----------------

extern "C" void kernel_launch(void* const* d_in, const int* in_sizes, int n_in,
                              void* d_out, int out_size, void* d_ws, size_t ws_size,
                              hipStream_t stream) {
  const float* values = (const float*)d_in[0];
  const int*   indices= (const int*)  d_in[1];
  const float* maskv  = (const float*)d_in[2];
  const float* kern1  = (const float*)d_in[3];
  const float* bias1  = (const float*)d_in[4];
  const float* kern2  = (const float*)d_in[5];
  const float* bias2  = (const float*)d_in[6];
  float* out = (float*)d_out;

  char* ws = (char*)d_ws;
  size_t off = 0;
  auto alloc = [&](size_t bytes) { void* p = ws + off; off = (off + bytes + 255) & ~(size_t)255; return p; };
  int*      map      = (int*)     alloc(GVOX*4);            // 1 MB
  int*      pcoord   = (int*)     alloc((NPTS+1)*4);
  int*      cls      = (int*)     alloc(NPTS*4);
  int*      sorted   = (int*)     alloc(NSLOT*4);
  int*      pcs      = (int*)     alloc(NSLOT*4);
  int*      tileclass= (int*)     alloc(MAXTILES*4);
  int*      nbr      = (int*)     alloc((size_t)MAXTILES*432*4);  // ~7 MB (fallback only)
  int*      cnt      = (int*)     alloc(27*4);
  int*      slot     = (int*)     alloc(27*4);
  int*      ntiles   = (int*)     alloc(4);
  _Float16* valsh    = (_Float16*)alloc((NPTS+1)*CCH*2);    // 4 MB
  _Float16* hh       = (_Float16*)alloc((NPTS+1)*CCH*2);    // 4 MB
  _Float16* wt1      = (_Float16*)alloc(27*CCH*CCH*2);
  _Float16* wt2      = (_Float16*)alloc(27*CCH*CCH*2);

  static int use_coop = -1;
  if (use_coop < 0) {
    int nb = 0;
    hipError_t e = hipOccupancyMaxActiveBlocksPerMultiprocessor(
        &nb, (const void*)mega3, NTHREADS, 0);
    use_coop = (e == hipSuccess && nb >= 1) ? 1 : 0;
  }

  if (use_coop) {
    void* args[] = { (void*)&values, (void*)&indices, (void*)&maskv,
                     (void*)&kern1, (void*)&bias1, (void*)&kern2, (void*)&bias2,
                     (void*)&map, (void*)&sorted, (void*)&pcs,
                     (void*)&cnt, (void*)&slot,
                     (void*)&valsh, (void*)&hh, (void*)&wt1, (void*)&wt2,
                     (void*)&out };
    hipError_t e = hipLaunchCooperativeKernel((void*)mega3, dim3(NBLOCKS),
                                              dim3(NTHREADS), args, 0, stream);
    if (e == hipSuccess) return;
    use_coop = 0;   // fall through to the verified multi-kernel path
  }

  k_prep0<<<(PREP0_THREADS + 255)/256, 256, 0, stream>>>(
      map, sorted, pcs, values, valsh, kern1, kern2, wt1, wt2, hh, pcoord, cnt, slot);
  k_prep1<<<NPTS/256, 256, 0, stream>>>(indices, map, pcoord, cls, cnt);
  k_prep3<<<NPTS/256 + (MAXTILES+255)/256, 256, 0, stream>>>(
      cls, cnt, slot, pcoord, sorted, pcs, tileclass, ntiles);
  k_nbr<<<(MAXTILES*432 + 255)/256, 256, 0, stream>>>(pcs, map, nbr);
  conv_mfma<0><<<(MAXTILES + 7)/8, 512, 0, stream>>>(valsh, nbr, sorted, tileclass,
                                                     ntiles, wt1, bias1, maskv, nullptr, hh, nullptr);
  conv_mfma<1><<<(MAXTILES + 7)/8, 512, 0, stream>>>(hh, nbr, sorted, tileclass,
                                                     ntiles, wt2, bias2, maskv, values, nullptr, out);
}